// Round 1
// baseline (483.915 us; speedup 1.0000x reference)
//
#include <hip/hip_runtime.h>
#include <hip/hip_bf16.h>

typedef __bf16 bf16;
typedef __bf16 bf16x4 __attribute__((ext_vector_type(4)));
typedef __bf16 bf16x8 __attribute__((ext_vector_type(8)));
typedef float  f32x4  __attribute__((ext_vector_type(4)));

#define MFMA(a,b,c) __builtin_amdgcn_mfma_f32_16x16x32_bf16((a),(b),(c),0,0,0)

// Problem constants
// B=8192, N=32, D=128, M=384, H=2, DK=192

// ---------------------------------------------------------------------------
// K0a: wqkT[n][j2] = sum_{c in head h} w_q[h*192+c][jmap(j2)] * w_k[h*192+c][k']
//      n = h*384 + k'  (768 rows), j2 in [0,256) with jmap skipping q's zero block
// grid 48 = h(2) * jt(4) * kt(6); fp32 compute, bf16 output.
// ---------------------------------------------------------------------------
__global__ __launch_bounds__(256) void k_wqk(const float* __restrict__ wq,
                                             const float* __restrict__ wk,
                                             bf16* __restrict__ wqkT) {
    const int blk = blockIdx.x;
    const int h = blk / 24, rem = blk % 24, jt = rem / 6, kt = rem % 6;
    __shared__ float Aq[96][64];
    __shared__ float Bk[96][64];
    const int t = threadIdx.x;
    const int jbase = (jt < 2) ? jt * 64 : jt * 64 + 128;   // skip q's zero cols 128..255
    const int kbase = kt * 64;
    const int jl = t & 63, kg = t >> 6;
    float acc[16];
#pragma unroll
    for (int i = 0; i < 16; ++i) acc[i] = 0.f;
    for (int half = 0; half < 2; ++half) {
        __syncthreads();
#pragma unroll
        for (int i = 0; i < 6; ++i) {
            int s = t + i * 256;               // 1536 slots = 96 rows * 16 float4
            int c = s >> 4, c4 = (s & 15) * 4;
            *(float4*)&Aq[c][c4] = *(const float4*)(wq + (h * 192 + half * 96 + c) * 384 + jbase + c4);
            *(float4*)&Bk[c][c4] = *(const float4*)(wk + (h * 192 + half * 96 + c) * 384 + kbase + c4);
        }
        __syncthreads();
        for (int c = 0; c < 96; ++c) {
            float a = Aq[c][jl];
#pragma unroll
            for (int kk = 0; kk < 16; ++kk) acc[kk] = fmaf(a, Bk[c][kg * 16 + kk], acc[kk]);
        }
    }
#pragma unroll
    for (int kk = 0; kk < 16; ++kk)
        wqkT[(h * 384 + kbase + kg * 16 + kk) * 256 + jt * 64 + jl] = (bf16)acc[kk];
}

// ---------------------------------------------------------------------------
// K0b: bf16 conversion of w_v, fc_w, mg_w1, mg_w2 (all kept (out,in) row-major = B^T form)
// ---------------------------------------------------------------------------
__global__ __launch_bounds__(256) void k_cvt(const float* __restrict__ wv, const float* __restrict__ fcw,
                                             const float* __restrict__ mg1, const float* __restrict__ mg2,
                                             bf16* __restrict__ o_wv, bf16* __restrict__ o_fc,
                                             bf16* __restrict__ o_mg1, bf16* __restrict__ o_mg2) {
    int idx = (blockIdx.x * 256 + threadIdx.x) * 4;    // 94208 threads * 4 = 376832 elements
    const float* src; bf16* dst; int off;
    if (idx < 147456)      { src = wv;  dst = o_wv;  off = idx; }
    else if (idx < 294912) { src = fcw; dst = o_fc;  off = idx - 147456; }
    else if (idx < 360448) { src = mg1; dst = o_mg1; off = idx - 294912; }
    else                   { src = mg2; dst = o_mg2; off = idx - 360448; }
    float4 v = *(const float4*)(src + off);
    bf16x4 o = {(bf16)v.x, (bf16)v.y, (bf16)v.z, (bf16)v.w};
    *(bf16x4*)(dst + off) = o;
}

// ---------------------------------------------------------------------------
// K1: qwk[b][n] = q_eff[b] @ wqkT   (M=8192, K=256, N=768), MFMA 16x16x32 bf16
//     q_eff = [src | src_t] (zero block dropped). 32 rows/block.
// ---------------------------------------------------------------------------
__global__ __launch_bounds__(256) void k_qwk(const float* __restrict__ src, const float* __restrict__ srct,
                                             const bf16* __restrict__ wqkT, float* __restrict__ qwk) {
    const int b0 = blockIdx.x * 32;
    __shared__ bf16 qA[32][264];      // pitch 264 bf16 (pad 8) -> 16B-aligned rows
    const int t = threadIdx.x;
#pragma unroll
    for (int i = 0; i < 8; ++i) {
        int s = t + i * 256;           // 2048 float4 slots
        int row = s >> 6, col4 = (s & 63) * 4;
        const float* p = (col4 < 128) ? (src + (b0 + row) * 128 + col4)
                                      : (srct + (b0 + row) * 128 + (col4 - 128));
        float4 v = *(const float4*)p;
        bf16x4 o = {(bf16)v.x, (bf16)v.y, (bf16)v.z, (bf16)v.w};
        *(bf16x4*)&qA[row][col4] = o;
    }
    __syncthreads();
    const int lane = t & 63, wave = t >> 6;
    const int l15 = lane & 15, quad = lane >> 4;
    bf16x8 af[2][8];
#pragma unroll
    for (int m = 0; m < 2; ++m)
#pragma unroll
        for (int kt = 0; kt < 8; ++kt)
            af[m][kt] = *(const bf16x8*)&qA[m * 16 + l15][kt * 32 + quad * 8];
    for (int i = 0; i < 12; ++i) {
        int nt = wave + i * 4;          // 48 n-tiles
        f32x4 c0 = {0.f, 0.f, 0.f, 0.f}, c1 = {0.f, 0.f, 0.f, 0.f};
        const bf16* bp = wqkT + (nt * 16 + l15) * 256 + quad * 8;
#pragma unroll
        for (int kt = 0; kt < 8; ++kt) {
            bf16x8 bv = *(const bf16x8*)(bp + kt * 32);
            c0 = MFMA(af[0][kt], bv, c0);
            c1 = MFMA(af[1][kt], bv, c1);
        }
        int col = nt * 16 + l15;
#pragma unroll
        for (int r = 0; r < 4; ++r) {
            qwk[(b0 + quad * 4 + r) * 768 + col]      = c0[r];
            qwk[(b0 + 16 + quad * 4 + r) * 768 + col] = c1[r];
        }
    }
}

// ---------------------------------------------------------------------------
// K2 (dominant, HBM-bound): one block per batch.
//  kin = [seq | seq_e | seq_t] staged fp32 in LDS (pitch 385 -> conflict-free),
//  scores = kin . qwk (VALU), masked softmax (shuffle), attn -> d_out,
//  ctx[h,k] = sum_n attn*kin -> bf16 ws.
// ---------------------------------------------------------------------------
__global__ __launch_bounds__(256) void k_attn(const float* __restrict__ seq, const float* __restrict__ seqe,
                                              const float* __restrict__ seqt, const float* __restrict__ qwk,
                                              const int* __restrict__ mask, float* __restrict__ attnw,
                                              bf16* __restrict__ ctx) {
    const int b = blockIdx.x;
    __shared__ float kin[32][385];
    __shared__ float qv[768];
    __shared__ float sp[256];
    __shared__ float att[64];
    __shared__ int   msk[32];
    const int t = threadIdx.x;
    {
        const float* p0 = seq  + (size_t)b * 4096;
        const float* p1 = seqe + (size_t)b * 4096;
        const float* p2 = seqt + (size_t)b * 4096;
#pragma unroll
        for (int i = 0; i < 4; ++i) {
            int s = t + i * 256;                 // 1024 float4 per source
            int row = s >> 5, col = (s & 31) * 4;
            float4 v0 = *(const float4*)(p0 + s * 4);
            float4 v1 = *(const float4*)(p1 + s * 4);
            float4 v2 = *(const float4*)(p2 + s * 4);
            float* k0 = &kin[row][col];
            k0[0] = v0.x; k0[1] = v0.y; k0[2] = v0.z; k0[3] = v0.w;
            float* k1 = &kin[row][col + 128];
            k1[0] = v1.x; k1[1] = v1.y; k1[2] = v1.z; k1[3] = v1.w;
            float* k2 = &kin[row][col + 256];
            k2[0] = v2.x; k2[1] = v2.y; k2[2] = v2.z; k2[3] = v2.w;
        }
    }
    if (t < 192) *(float4*)&qv[t * 4] = *(const float4*)(qwk + (size_t)b * 768 + t * 4);
    if (t < 32) msk[t] = mask[b * 32 + t];
    __syncthreads();
    {   // partial dot products: t = (q<<6) | (h<<5) | n, each covers 96 of k
        const int n = t & 31, h = (t >> 5) & 1, q = t >> 6;
        const float* kp = &kin[n][q * 96];
        const float* qp = &qv[h * 384 + q * 96];
        float s = 0.f;
        for (int k = 0; k < 96; ++k) s = fmaf(kp[k], qp[k], s);
        sp[t] = s;
    }
    __syncthreads();
    if (t < 64) {
        const int n = t & 31, h = t >> 5;
        float s = (sp[t] + sp[t + 64] + sp[t + 128] + sp[t + 192]) * 0.07216878364870323f;
        if (msk[n]) s = -1e10f;
        float m = s;
#pragma unroll
        for (int off = 16; off > 0; off >>= 1) m = fmaxf(m, __shfl_xor(m, off, 32));
        float e = __expf(s - m);
        float l = e;
#pragma unroll
        for (int off = 16; off > 0; off >>= 1) l += __shfl_xor(l, off, 32);
        float a = e / l;
        att[t] = a;
        attnw[((size_t)h * 8192 + b) * 32 + n] = a;
    }
    __syncthreads();
#pragma unroll
    for (int i = 0; i < 3; ++i) {
        int o = t + i * 256;                 // 768 ctx values
        int h = (o >= 384) ? 1 : 0;
        int k = o - h * 384;
        const float* ap = &att[h * 32];
        float c = 0.f;
#pragma unroll 8
        for (int n = 0; n < 32; ++n) c = fmaf(ap[n], kin[n][k], c);
        ctx[(size_t)b * 768 + o] = (bf16)c;
    }
}

// ---------------------------------------------------------------------------
// K3 tail: per 16 batch rows: out = ctx@w_v^T (per-head) -> fc+bias -> LN ->
//          [ln|src]@mg_w1^T+b relu -> @mg_w2^T+b -> merged.
// ---------------------------------------------------------------------------
__global__ __launch_bounds__(256) void k_tail(const bf16* __restrict__ ctx, const float* __restrict__ srcv,
                                              const bf16* __restrict__ wvb, const bf16* __restrict__ fcwb,
                                              const float* __restrict__ fcb, const float* __restrict__ lng,
                                              const float* __restrict__ lnb, const bf16* __restrict__ mg1b,
                                              const float* __restrict__ mgb1, const bf16* __restrict__ mg2b,
                                              const float* __restrict__ mgb2, float* __restrict__ out) {
    const int b0 = blockIdx.x * 16;
    __shared__ __align__(16) char smem[59520];
    bf16*  ctxA  = (bf16*)smem;               // [16][776]  (dies after out-proj)
    float* fcbuf = (float*)smem;              // [16][385]  (aliases ctxA, used after)
    bf16*  aout  = (bf16*)(smem + 24832);     // [16][392]
    bf16*  A2    = (bf16*)(smem + 37376);     // [16][520]
    bf16*  hbuf  = (bf16*)(smem + 54016);     // [16][136]
    float* red   = (float*)(smem + 58368);    // [2][16][8]
    float* stats = (float*)(smem + 59392);    // mu[16], rstd[16]
    const int t = threadIdx.x;
    const int lane = t & 63, wave = t >> 6, l15 = lane & 15, quad = lane >> 4;

    {   // stage ctx (bf16): 16 threads/row, 6 x 16B chunks each
        int row = t >> 4, cs = t & 15;
        const bf16* sp2 = ctx + (size_t)(b0 + row) * 768;
#pragma unroll
        for (int i = 0; i < 6; ++i) {
            int col = (cs + i * 16) * 8;
            *(bf16x8*)&ctxA[row * 776 + col] = *(const bf16x8*)(sp2 + col);
        }
    }
    __syncthreads();

    // ---- out-projection: attn_out = ctx_h @ w_v_h^T ----
    for (int h = 0; h < 2; ++h) {
        bf16x8 af[12];
#pragma unroll
        for (int kt = 0; kt < 12; ++kt)
            af[kt] = *(const bf16x8*)&ctxA[l15 * 776 + h * 384 + kt * 32 + quad * 8];
        const int nt0 = wave + 12 * h;
        const int cb0 = nt0 * 16, cb1 = (nt0 + 4) * 16, cb2 = (nt0 + 8) * 16;
        f32x4 c0 = {0.f,0.f,0.f,0.f}, c1 = {0.f,0.f,0.f,0.f}, c2 = {0.f,0.f,0.f,0.f};
        const bf16* bp0 = wvb + (cb0 + l15) * 384 + quad * 8;
        const bf16* bp1 = wvb + (cb1 + l15) * 384 + quad * 8;
        const bf16* bp2 = wvb + (cb2 + l15) * 384 + quad * 8;
#pragma unroll
        for (int kt = 0; kt < 12; ++kt) {
            bf16x8 b0v = *(const bf16x8*)(bp0 + kt * 32);
            bf16x8 b1v = *(const bf16x8*)(bp1 + kt * 32);
            bf16x8 b2v = *(const bf16x8*)(bp2 + kt * 32);
            c0 = MFMA(af[kt], b0v, c0);
            c1 = MFMA(af[kt], b1v, c1);
            c2 = MFMA(af[kt], b2v, c2);
        }
#pragma unroll
        for (int r = 0; r < 4; ++r) {
            int row = quad * 4 + r;
            aout[row * 392 + cb0 + l15] = (bf16)c0[r];
            aout[row * 392 + cb1 + l15] = (bf16)c1[r];
            aout[row * 392 + cb2 + l15] = (bf16)c2[r];
        }
    }
    __syncthreads();

    // ---- fc: fcbuf = attn_out @ fc_w^T + fc_b  (fp32 in LDS; aliases dead ctxA) ----
    {
        bf16x8 af[12];
#pragma unroll
        for (int kt = 0; kt < 12; ++kt)
            af[kt] = *(const bf16x8*)&aout[l15 * 392 + kt * 32 + quad * 8];
#pragma unroll
        for (int g = 0; g < 2; ++g) {
            const int cbA = (wave + 4 * (3 * g + 0)) * 16;
            const int cbB = (wave + 4 * (3 * g + 1)) * 16;
            const int cbC = (wave + 4 * (3 * g + 2)) * 16;
            f32x4 cA = {0.f,0.f,0.f,0.f}, cB = {0.f,0.f,0.f,0.f}, cC = {0.f,0.f,0.f,0.f};
            const bf16* bpA = fcwb + (cbA + l15) * 384 + quad * 8;
            const bf16* bpB = fcwb + (cbB + l15) * 384 + quad * 8;
            const bf16* bpC = fcwb + (cbC + l15) * 384 + quad * 8;
#pragma unroll
            for (int kt = 0; kt < 12; ++kt) {
                bf16x8 bA = *(const bf16x8*)(bpA + kt * 32);
                bf16x8 bB = *(const bf16x8*)(bpB + kt * 32);
                bf16x8 bC = *(const bf16x8*)(bpC + kt * 32);
                cA = MFMA(af[kt], bA, cA);
                cB = MFMA(af[kt], bB, cB);
                cC = MFMA(af[kt], bC, cC);
            }
            float biasA = fcb[cbA + l15], biasB = fcb[cbB + l15], biasC = fcb[cbC + l15];
#pragma unroll
            for (int r = 0; r < 4; ++r) {
                int row = quad * 4 + r;
                fcbuf[row * 385 + cbA + l15] = cA[r] + biasA;
                fcbuf[row * 385 + cbB + l15] = cB[r] + biasB;
                fcbuf[row * 385 + cbC + l15] = cC[r] + biasC;
            }
        }
    }
    __syncthreads();

    // ---- LayerNorm (fp32) ----
    if (t < 128) {
        int row = t >> 3, qq = t & 7;
        const float* p = &fcbuf[row * 385 + qq * 48];
        float s = 0.f, sq = 0.f;
        for (int k = 0; k < 48; ++k) { float x = p[k]; s += x; sq = fmaf(x, x, sq); }
        red[row * 8 + qq]       = s;
        red[128 + row * 8 + qq] = sq;
    }
    __syncthreads();
    if (t < 16) {
        float s = 0.f, sq = 0.f;
#pragma unroll
        for (int i = 0; i < 8; ++i) { s += red[t * 8 + i]; sq += red[128 + t * 8 + i]; }
        float mu = s * (1.0f / 384.0f);
        float var = sq * (1.0f / 384.0f) - mu * mu;
        stats[t] = mu;
        stats[16 + t] = rsqrtf(var + 1e-5f);
    }
    __syncthreads();
    {   // normalize -> A2 cols 0..383 ; stage src -> A2 cols 384..511
        int row = t >> 4, cs = t & 15;
        float mu = stats[row], rs = stats[16 + row];
#pragma unroll
        for (int i = 0; i < 24; ++i) {
            int col = cs * 24 + i;
            float x = fcbuf[row * 385 + col];
            A2[row * 520 + col] = (bf16)((x - mu) * rs * lng[col] + lnb[col]);
        }
        const float* sp2 = srcv + (size_t)(b0 + row) * 128 + cs * 8;
#pragma unroll
        for (int i = 0; i < 8; ++i)
            A2[row * 520 + 384 + cs * 8 + i] = (bf16)sp2[i];
    }
    __syncthreads();

    // ---- mg1: h = relu([ln|src] @ mg_w1^T + b1) ----
    {
        bf16x8 af[16];
#pragma unroll
        for (int kt = 0; kt < 16; ++kt)
            af[kt] = *(const bf16x8*)&A2[l15 * 520 + kt * 32 + quad * 8];
        const int cbA = wave * 16, cbB = (wave + 4) * 16;
        f32x4 cA = {0.f,0.f,0.f,0.f}, cB = {0.f,0.f,0.f,0.f};
        const bf16* bpA = mg1b + (cbA + l15) * 512 + quad * 8;
        const bf16* bpB = mg1b + (cbB + l15) * 512 + quad * 8;
#pragma unroll
        for (int kt = 0; kt < 16; ++kt) {
            bf16x8 bA = *(const bf16x8*)(bpA + kt * 32);
            bf16x8 bB = *(const bf16x8*)(bpB + kt * 32);
            cA = MFMA(af[kt], bA, cA);
            cB = MFMA(af[kt], bB, cB);
        }
        float biasA = mgb1[cbA + l15], biasB = mgb1[cbB + l15];
#pragma unroll
        for (int r = 0; r < 4; ++r) {
            int row = quad * 4 + r;
            hbuf[row * 136 + cbA + l15] = (bf16)fmaxf(cA[r] + biasA, 0.f);
            hbuf[row * 136 + cbB + l15] = (bf16)fmaxf(cB[r] + biasB, 0.f);
        }
    }
    __syncthreads();

    // ---- mg2: merged = h @ mg_w2^T + b2 -> d_out ----
    {
        bf16x8 af[4];
#pragma unroll
        for (int kt = 0; kt < 4; ++kt)
            af[kt] = *(const bf16x8*)&hbuf[l15 * 136 + kt * 32 + quad * 8];
        const int cbA = wave * 16, cbB = (wave + 4) * 16;
        f32x4 cA = {0.f,0.f,0.f,0.f}, cB = {0.f,0.f,0.f,0.f};
        const bf16* bpA = mg2b + (cbA + l15) * 128 + quad * 8;
        const bf16* bpB = mg2b + (cbB + l15) * 128 + quad * 8;
#pragma unroll
        for (int kt = 0; kt < 4; ++kt) {
            bf16x8 bA = *(const bf16x8*)(bpA + kt * 32);
            bf16x8 bB = *(const bf16x8*)(bpB + kt * 32);
            cA = MFMA(af[kt], bA, cA);
            cB = MFMA(af[kt], bB, cB);
        }
        float biasA = mgb2[cbA + l15], biasB = mgb2[cbB + l15];
#pragma unroll
        for (int r = 0; r < 4; ++r) {
            int row = b0 + quad * 4 + r;
            out[(size_t)row * 128 + cbA + l15] = cA[r] + biasA;
            out[(size_t)row * 128 + cbB + l15] = cB[r] + biasB;
        }
    }
}

// ---------------------------------------------------------------------------
extern "C" void kernel_launch(void* const* d_in, const int* in_sizes, int n_in,
                              void* d_out, int out_size, void* d_ws, size_t ws_size,
                              hipStream_t stream) {
    (void)in_sizes; (void)n_in; (void)out_size; (void)ws_size;
    const float* src  = (const float*)d_in[0];
    const float* srct = (const float*)d_in[1];
    const float* seq  = (const float*)d_in[2];
    const float* seqt = (const float*)d_in[3];
    const float* seqe = (const float*)d_in[4];
    // d_in[5] = time_diff (unused by reference)
    const int*   mask = (const int*)d_in[6];
    const float* wq   = (const float*)d_in[7];
    const float* wk   = (const float*)d_in[8];
    const float* wv   = (const float*)d_in[9];
    const float* fcw  = (const float*)d_in[10];
    const float* fcb  = (const float*)d_in[11];
    const float* lng  = (const float*)d_in[12];
    const float* lnb  = (const float*)d_in[13];
    const float* mg1  = (const float*)d_in[14];
    const float* mgb1 = (const float*)d_in[15];
    const float* mg2  = (const float*)d_in[16];
    const float* mgb2 = (const float*)d_in[17];

    char* ws = (char*)d_ws;
    bf16*  wqkT  = (bf16*)(ws);                // 768*256*2      = 393216
    bf16*  wv_b  = (bf16*)(ws + 393216);       // 147456*2       = 294912
    bf16*  fc_b  = (bf16*)(ws + 688128);       // 147456*2       = 294912
    bf16*  mg1_b = (bf16*)(ws + 983040);       // 65536*2        = 131072
    bf16*  mg2_b = (bf16*)(ws + 1114112);      // 16384*2        = 32768
    float* qwk   = (float*)(ws + 1146880);     // 8192*768*4     = 25165824
    bf16*  ctx   = (bf16*)(ws + 26312704);     // 8192*768*2     = 12582912  (ends 38895616)

    float* merged = (float*)d_out;
    float* attnw  = merged + (size_t)8192 * 128;

    k_wqk <<<48,   256, 0, stream>>>(wq, wk, wqkT);
    k_cvt <<<368,  256, 0, stream>>>(wv, fcw, mg1, mg2, wv_b, fc_b, mg1_b, mg2_b);
    k_qwk <<<256,  256, 0, stream>>>(src, srct, wqkT, qwk);
    k_attn<<<8192, 256, 0, stream>>>(seq, seqe, seqt, qwk, mask, attnw, ctx);
    k_tail<<<512,  256, 0, stream>>>(ctx, src, wv_b, fc_b, fcb, lng, lnb,
                                     mg1_b, mgb1, mg2_b, mgb2, merged);
}

// Round 3
// 481.296 us; speedup vs baseline: 1.0054x; 1.0054x over previous
//
#include <hip/hip_runtime.h>
#include <hip/hip_bf16.h>

typedef __bf16 bf16;
typedef __bf16 bf16x4 __attribute__((ext_vector_type(4)));
typedef __bf16 bf16x8 __attribute__((ext_vector_type(8)));
typedef float  f32x4  __attribute__((ext_vector_type(4)));

#define MFMA(a,b,c) __builtin_amdgcn_mfma_f32_16x16x32_bf16((a),(b),(c),0,0,0)

// Problem constants
// B=8192, N=32, D=128, M=384, H=2, DK=192

// ---------------------------------------------------------------------------
// K0a: wqkT[n][j2] = sum_{c in head h} w_q[h*192+c][jmap(j2)] * w_k[h*192+c][k']
//      n = h*384 + k'  (768 rows), j2 in [0,256) with jmap skipping q's zero block
// grid 48 = h(2) * jt(4) * kt(6); fp32 compute, bf16 output.
// ---------------------------------------------------------------------------
__global__ __launch_bounds__(256) void k_wqk(const float* __restrict__ wq,
                                             const float* __restrict__ wk,
                                             bf16* __restrict__ wqkT) {
    const int blk = blockIdx.x;
    const int h = blk / 24, rem = blk % 24, jt = rem / 6, kt = rem % 6;
    __shared__ float Aq[96][64];
    __shared__ float Bk[96][64];
    const int t = threadIdx.x;
    const int jbase = (jt < 2) ? jt * 64 : jt * 64 + 128;   // skip q's zero cols 128..255
    const int kbase = kt * 64;
    const int jl = t & 63, kg = t >> 6;
    float acc[16];
#pragma unroll
    for (int i = 0; i < 16; ++i) acc[i] = 0.f;
    for (int half = 0; half < 2; ++half) {
        __syncthreads();
#pragma unroll
        for (int i = 0; i < 6; ++i) {
            int s = t + i * 256;               // 1536 slots = 96 rows * 16 float4
            int c = s >> 4, c4 = (s & 15) * 4;
            *(float4*)&Aq[c][c4] = *(const float4*)(wq + (h * 192 + half * 96 + c) * 384 + jbase + c4);
            *(float4*)&Bk[c][c4] = *(const float4*)(wk + (h * 192 + half * 96 + c) * 384 + kbase + c4);
        }
        __syncthreads();
        for (int c = 0; c < 96; ++c) {
            float a = Aq[c][jl];
#pragma unroll
            for (int kk = 0; kk < 16; ++kk) acc[kk] = fmaf(a, Bk[c][kg * 16 + kk], acc[kk]);
        }
    }
#pragma unroll
    for (int kk = 0; kk < 16; ++kk)
        wqkT[(h * 384 + kbase + kg * 16 + kk) * 256 + jt * 64 + jl] = (bf16)acc[kk];
}

// ---------------------------------------------------------------------------
// K0b: bf16 conversion of w_v, fc_w, mg_w1, mg_w2 (all kept (out,in) row-major = B^T form)
// ---------------------------------------------------------------------------
__global__ __launch_bounds__(256) void k_cvt(const float* __restrict__ wv, const float* __restrict__ fcw,
                                             const float* __restrict__ mg1, const float* __restrict__ mg2,
                                             bf16* __restrict__ o_wv, bf16* __restrict__ o_fc,
                                             bf16* __restrict__ o_mg1, bf16* __restrict__ o_mg2) {
    int idx = (blockIdx.x * 256 + threadIdx.x) * 4;    // 94208 threads * 4 = 376832 elements
    const float* src; bf16* dst; int off;
    if (idx < 147456)      { src = wv;  dst = o_wv;  off = idx; }
    else if (idx < 294912) { src = fcw; dst = o_fc;  off = idx - 147456; }
    else if (idx < 360448) { src = mg1; dst = o_mg1; off = idx - 294912; }
    else                   { src = mg2; dst = o_mg2; off = idx - 360448; }
    float4 v = *(const float4*)(src + off);
    bf16x4 o = {(bf16)v.x, (bf16)v.y, (bf16)v.z, (bf16)v.w};
    *(bf16x4*)(dst + off) = o;
}

// ---------------------------------------------------------------------------
// K1: qwk[b][n] = q_eff[b] @ wqkT   (M=8192, K=256, N=768), MFMA 16x16x32 bf16
//     q_eff = [src | src_t] (zero block dropped). 32 rows/block.
// ---------------------------------------------------------------------------
__global__ __launch_bounds__(256) void k_qwk(const float* __restrict__ src, const float* __restrict__ srct,
                                             const bf16* __restrict__ wqkT, float* __restrict__ qwk) {
    const int b0 = blockIdx.x * 32;
    __shared__ bf16 qA[32][264];      // pitch 264 bf16 (pad 8) -> 16B-aligned rows
    const int t = threadIdx.x;
#pragma unroll
    for (int i = 0; i < 8; ++i) {
        int s = t + i * 256;           // 2048 float4 slots
        int row = s >> 6, col4 = (s & 63) * 4;
        const float* p = (col4 < 128) ? (src + (b0 + row) * 128 + col4)
                                      : (srct + (b0 + row) * 128 + (col4 - 128));
        float4 v = *(const float4*)p;
        bf16x4 o = {(bf16)v.x, (bf16)v.y, (bf16)v.z, (bf16)v.w};
        *(bf16x4*)&qA[row][col4] = o;
    }
    __syncthreads();
    const int lane = t & 63, wave = t >> 6;
    const int l15 = lane & 15, quad = lane >> 4;
    bf16x8 af[2][8];
#pragma unroll
    for (int m = 0; m < 2; ++m)
#pragma unroll
        for (int kt = 0; kt < 8; ++kt)
            af[m][kt] = *(const bf16x8*)&qA[m * 16 + l15][kt * 32 + quad * 8];
    for (int i = 0; i < 12; ++i) {
        int nt = wave + i * 4;          // 48 n-tiles
        f32x4 c0 = {0.f, 0.f, 0.f, 0.f}, c1 = {0.f, 0.f, 0.f, 0.f};
        const bf16* bp = wqkT + (nt * 16 + l15) * 256 + quad * 8;
#pragma unroll
        for (int kt = 0; kt < 8; ++kt) {
            bf16x8 bv = *(const bf16x8*)(bp + kt * 32);
            c0 = MFMA(af[0][kt], bv, c0);
            c1 = MFMA(af[1][kt], bv, c1);
        }
        int col = nt * 16 + l15;
#pragma unroll
        for (int r = 0; r < 4; ++r) {
            qwk[(b0 + quad * 4 + r) * 768 + col]      = c0[r];
            qwk[(b0 + 16 + quad * 4 + r) * 768 + col] = c1[r];
        }
    }
}

// ---------------------------------------------------------------------------
// K2 (dominant): one block per batch. ONLY change vs R1: kin staged as bf16
// (pitch 392, rows 16B-aligned) -> LDS 29.5 KB total -> 5 blocks/CU.
// Same loop structure as the passing R1 kernel otherwise.
// ---------------------------------------------------------------------------
__global__ __launch_bounds__(256) void k_attn(const float* __restrict__ seq, const float* __restrict__ seqe,
                                              const float* __restrict__ seqt, const float* __restrict__ qwk,
                                              const int* __restrict__ mask, float* __restrict__ attnw,
                                              bf16* __restrict__ ctx) {
    const int b = blockIdx.x;
    __shared__ bf16 kin[32][392];
    __shared__ float qv[768];
    __shared__ float sp[256];
    __shared__ float att[64];
    __shared__ int   msk[32];
    const int t = threadIdx.x;
    {
        const float* p0 = seq  + (size_t)b * 4096;
        const float* p1 = seqe + (size_t)b * 4096;
        const float* p2 = seqt + (size_t)b * 4096;
#pragma unroll
        for (int i = 0; i < 4; ++i) {
            int s = t + i * 256;                 // 1024 float4 per source
            int row = s >> 5, col = (s & 31) * 4;
            float4 v0 = *(const float4*)(p0 + s * 4);
            float4 v1 = *(const float4*)(p1 + s * 4);
            float4 v2 = *(const float4*)(p2 + s * 4);
            bf16x4 o0 = {(bf16)v0.x, (bf16)v0.y, (bf16)v0.z, (bf16)v0.w};
            bf16x4 o1 = {(bf16)v1.x, (bf16)v1.y, (bf16)v1.z, (bf16)v1.w};
            bf16x4 o2 = {(bf16)v2.x, (bf16)v2.y, (bf16)v2.z, (bf16)v2.w};
            *(bf16x4*)&kin[row][col]       = o0;
            *(bf16x4*)&kin[row][col + 128] = o1;
            *(bf16x4*)&kin[row][col + 256] = o2;
        }
    }
    if (t < 192) *(float4*)&qv[t * 4] = *(const float4*)(qwk + (size_t)b * 768 + t * 4);
    if (t < 32) msk[t] = mask[b * 32 + t];
    __syncthreads();
    {   // partial dot products: t = (q<<6) | (h<<5) | n, each covers 96 of k
        const int n = t & 31, h = (t >> 5) & 1, q = t >> 6;
        const bf16* kp = &kin[n][q * 96];
        const float* qp = &qv[h * 384 + q * 96];
        float s = 0.f;
        for (int k = 0; k < 96; ++k) s = fmaf((float)kp[k], qp[k], s);
        sp[t] = s;
    }
    __syncthreads();
    if (t < 64) {
        const int n = t & 31, h = t >> 5;
        float s = (sp[t] + sp[t + 64] + sp[t + 128] + sp[t + 192]) * 0.07216878364870323f;
        if (msk[n]) s = -1e10f;
        float m = s;
#pragma unroll
        for (int off = 16; off > 0; off >>= 1) m = fmaxf(m, __shfl_xor(m, off, 32));
        float e = __expf(s - m);
        float l = e;
#pragma unroll
        for (int off = 16; off > 0; off >>= 1) l += __shfl_xor(l, off, 32);
        float a = e / l;
        att[t] = a;
        attnw[((size_t)h * 8192 + b) * 32 + n] = a;
    }
    __syncthreads();
#pragma unroll
    for (int i = 0; i < 3; ++i) {
        int o = t + i * 256;                 // 768 ctx values
        int h = (o >= 384) ? 1 : 0;
        int k = o - h * 384;
        const float* ap = &att[h * 32];
        float c = 0.f;
#pragma unroll 8
        for (int n = 0; n < 32; ++n) c = fmaf(ap[n], (float)kin[n][k], c);
        ctx[(size_t)b * 768 + o] = (bf16)c;
    }
}

// ---------------------------------------------------------------------------
// K3 tail: per 16 batch rows: out = ctx@w_v^T (per-head) -> fc+bias -> LN ->
//          [ln|src]@mg_w1^T+b relu -> @mg_w2^T+b -> merged.   (R1 verbatim)
// ---------------------------------------------------------------------------
__global__ __launch_bounds__(256) void k_tail(const bf16* __restrict__ ctx, const float* __restrict__ srcv,
                                              const bf16* __restrict__ wvb, const bf16* __restrict__ fcwb,
                                              const float* __restrict__ fcb, const float* __restrict__ lng,
                                              const float* __restrict__ lnb, const bf16* __restrict__ mg1b,
                                              const float* __restrict__ mgb1, const bf16* __restrict__ mg2b,
                                              const float* __restrict__ mgb2, float* __restrict__ out) {
    const int b0 = blockIdx.x * 16;
    __shared__ __align__(16) char smem[59520];
    bf16*  ctxA  = (bf16*)smem;               // [16][776]  (dies after out-proj)
    float* fcbuf = (float*)smem;              // [16][385]  (aliases ctxA, used after)
    bf16*  aout  = (bf16*)(smem + 24832);     // [16][392]
    bf16*  A2    = (bf16*)(smem + 37376);     // [16][520]
    bf16*  hbuf  = (bf16*)(smem + 54016);     // [16][136]
    float* red   = (float*)(smem + 58368);    // [2][16][8]
    float* stats = (float*)(smem + 59392);    // mu[16], rstd[16]
    const int t = threadIdx.x;
    const int lane = t & 63, wave = t >> 6, l15 = lane & 15, quad = lane >> 4;

    {   // stage ctx (bf16): 16 threads/row, 6 x 16B chunks each
        int row = t >> 4, cs = t & 15;
        const bf16* sp2 = ctx + (size_t)(b0 + row) * 768;
#pragma unroll
        for (int i = 0; i < 6; ++i) {
            int col = (cs + i * 16) * 8;
            *(bf16x8*)&ctxA[row * 776 + col] = *(const bf16x8*)(sp2 + col);
        }
    }
    __syncthreads();

    // ---- out-projection: attn_out = ctx_h @ w_v_h^T ----
    for (int h = 0; h < 2; ++h) {
        bf16x8 af[12];
#pragma unroll
        for (int kt = 0; kt < 12; ++kt)
            af[kt] = *(const bf16x8*)&ctxA[l15 * 776 + h * 384 + kt * 32 + quad * 8];
        const int nt0 = wave + 12 * h;
        const int cb0 = nt0 * 16, cb1 = (nt0 + 4) * 16, cb2 = (nt0 + 8) * 16;
        f32x4 c0 = {0.f,0.f,0.f,0.f}, c1 = {0.f,0.f,0.f,0.f}, c2 = {0.f,0.f,0.f,0.f};
        const bf16* bp0 = wvb + (cb0 + l15) * 384 + quad * 8;
        const bf16* bp1 = wvb + (cb1 + l15) * 384 + quad * 8;
        const bf16* bp2 = wvb + (cb2 + l15) * 384 + quad * 8;
#pragma unroll
        for (int kt = 0; kt < 12; ++kt) {
            bf16x8 b0v = *(const bf16x8*)(bp0 + kt * 32);
            bf16x8 b1v = *(const bf16x8*)(bp1 + kt * 32);
            bf16x8 b2v = *(const bf16x8*)(bp2 + kt * 32);
            c0 = MFMA(af[kt], b0v, c0);
            c1 = MFMA(af[kt], b1v, c1);
            c2 = MFMA(af[kt], b2v, c2);
        }
#pragma unroll
        for (int r = 0; r < 4; ++r) {
            int row = quad * 4 + r;
            aout[row * 392 + cb0 + l15] = (bf16)c0[r];
            aout[row * 392 + cb1 + l15] = (bf16)c1[r];
            aout[row * 392 + cb2 + l15] = (bf16)c2[r];
        }
    }
    __syncthreads();

    // ---- fc: fcbuf = attn_out @ fc_w^T + fc_b  (fp32 in LDS; aliases dead ctxA) ----
    {
        bf16x8 af[12];
#pragma unroll
        for (int kt = 0; kt < 12; ++kt)
            af[kt] = *(const bf16x8*)&aout[l15 * 392 + kt * 32 + quad * 8];
#pragma unroll
        for (int g = 0; g < 2; ++g) {
            const int cbA = (wave + 4 * (3 * g + 0)) * 16;
            const int cbB = (wave + 4 * (3 * g + 1)) * 16;
            const int cbC = (wave + 4 * (3 * g + 2)) * 16;
            f32x4 cA = {0.f,0.f,0.f,0.f}, cB = {0.f,0.f,0.f,0.f}, cC = {0.f,0.f,0.f,0.f};
            const bf16* bpA = fcwb + (cbA + l15) * 384 + quad * 8;
            const bf16* bpB = fcwb + (cbB + l15) * 384 + quad * 8;
            const bf16* bpC = fcwb + (cbC + l15) * 384 + quad * 8;
#pragma unroll
            for (int kt = 0; kt < 12; ++kt) {
                bf16x8 bA = *(const bf16x8*)(bpA + kt * 32);
                bf16x8 bB = *(const bf16x8*)(bpB + kt * 32);
                bf16x8 bC = *(const bf16x8*)(bpC + kt * 32);
                cA = MFMA(af[kt], bA, cA);
                cB = MFMA(af[kt], bB, cB);
                cC = MFMA(af[kt], bC, cC);
            }
            float biasA = fcb[cbA + l15], biasB = fcb[cbB + l15], biasC = fcb[cbC + l15];
#pragma unroll
            for (int r = 0; r < 4; ++r) {
                int row = quad * 4 + r;
                fcbuf[row * 385 + cbA + l15] = cA[r] + biasA;
                fcbuf[row * 385 + cbB + l15] = cB[r] + biasB;
                fcbuf[row * 385 + cbC + l15] = cC[r] + biasC;
            }
        }
    }
    __syncthreads();

    // ---- LayerNorm (fp32) ----
    if (t < 128) {
        int row = t >> 3, qq = t & 7;
        const float* p = &fcbuf[row * 385 + qq * 48];
        float s = 0.f, sq = 0.f;
        for (int k = 0; k < 48; ++k) { float x = p[k]; s += x; sq = fmaf(x, x, sq); }
        red[row * 8 + qq]       = s;
        red[128 + row * 8 + qq] = sq;
    }
    __syncthreads();
    if (t < 16) {
        float s = 0.f, sq = 0.f;
#pragma unroll
        for (int i = 0; i < 8; ++i) { s += red[t * 8 + i]; sq += red[128 + t * 8 + i]; }
        float mu = s * (1.0f / 384.0f);
        float var = sq * (1.0f / 384.0f) - mu * mu;
        stats[t] = mu;
        stats[16 + t] = rsqrtf(var + 1e-5f);
    }
    __syncthreads();
    {   // normalize -> A2 cols 0..383 ; stage src -> A2 cols 384..511
        int row = t >> 4, cs = t & 15;
        float mu = stats[row], rs = stats[16 + row];
#pragma unroll
        for (int i = 0; i < 24; ++i) {
            int col = cs * 24 + i;
            float x = fcbuf[row * 385 + col];
            A2[row * 520 + col] = (bf16)((x - mu) * rs * lng[col] + lnb[col]);
        }
        const float* sp2 = srcv + (size_t)(b0 + row) * 128 + cs * 8;
#pragma unroll
        for (int i = 0; i < 8; ++i)
            A2[row * 520 + 384 + cs * 8 + i] = (bf16)sp2[i];
    }
    __syncthreads();

    // ---- mg1: h = relu([ln|src] @ mg_w1^T + b1) ----
    {
        bf16x8 af[16];
#pragma unroll
        for (int kt = 0; kt < 16; ++kt)
            af[kt] = *(const bf16x8*)&A2[l15 * 520 + kt * 32 + quad * 8];
        const int cbA = wave * 16, cbB = (wave + 4) * 16;
        f32x4 cA = {0.f,0.f,0.f,0.f}, cB = {0.f,0.f,0.f,0.f};
        const bf16* bpA = mg1b + (cbA + l15) * 512 + quad * 8;
        const bf16* bpB = mg1b + (cbB + l15) * 512 + quad * 8;
#pragma unroll
        for (int kt = 0; kt < 16; ++kt) {
            bf16x8 bA = *(const bf16x8*)(bpA + kt * 32);
            bf16x8 bB = *(const bf16x8*)(bpB + kt * 32);
            cA = MFMA(af[kt], bA, cA);
            cB = MFMA(af[kt], bB, cB);
        }
        float biasA = mgb1[cbA + l15], biasB = mgb1[cbB + l15];
#pragma unroll
        for (int r = 0; r < 4; ++r) {
            int row = quad * 4 + r;
            hbuf[row * 136 + cbA + l15] = (bf16)fmaxf(cA[r] + biasA, 0.f);
            hbuf[row * 136 + cbB + l15] = (bf16)fmaxf(cB[r] + biasB, 0.f);
        }
    }
    __syncthreads();

    // ---- mg2: merged = h @ mg_w2^T + b2 -> d_out ----
    {
        bf16x8 af[4];
#pragma unroll
        for (int kt = 0; kt < 4; ++kt)
            af[kt] = *(const bf16x8*)&hbuf[l15 * 136 + kt * 32 + quad * 8];
        const int cbA = wave * 16, cbB = (wave + 4) * 16;
        f32x4 cA = {0.f,0.f,0.f,0.f}, cB = {0.f,0.f,0.f,0.f};
        const bf16* bpA = mg2b + (cbA + l15) * 128 + quad * 8;
        const bf16* bpB = mg2b + (cbB + l15) * 128 + quad * 8;
#pragma unroll
        for (int kt = 0; kt < 4; ++kt) {
            bf16x8 bA = *(const bf16x8*)(bpA + kt * 32);
            bf16x8 bB = *(const bf16x8*)(bpB + kt * 32);
            cA = MFMA(af[kt], bA, cA);
            cB = MFMA(af[kt], bB, cB);
        }
        float biasA = mgb2[cbA + l15], biasB = mgb2[cbB + l15];
#pragma unroll
        for (int r = 0; r < 4; ++r) {
            int row = b0 + quad * 4 + r;
            out[(size_t)row * 128 + cbA + l15] = cA[r] + biasA;
            out[(size_t)row * 128 + cbB + l15] = cB[r] + biasB;
        }
    }
}

// ---------------------------------------------------------------------------
extern "C" void kernel_launch(void* const* d_in, const int* in_sizes, int n_in,
                              void* d_out, int out_size, void* d_ws, size_t ws_size,
                              hipStream_t stream) {
    (void)in_sizes; (void)n_in; (void)out_size; (void)ws_size;
    const float* src  = (const float*)d_in[0];
    const float* srct = (const float*)d_in[1];
    const float* seq  = (const float*)d_in[2];
    const float* seqt = (const float*)d_in[3];
    const float* seqe = (const float*)d_in[4];
    // d_in[5] = time_diff (unused by reference)
    const int*   mask = (const int*)d_in[6];
    const float* wq   = (const float*)d_in[7];
    const float* wk   = (const float*)d_in[8];
    const float* wv   = (const float*)d_in[9];
    const float* fcw  = (const float*)d_in[10];
    const float* fcb  = (const float*)d_in[11];
    const float* lng  = (const float*)d_in[12];
    const float* lnb  = (const float*)d_in[13];
    const float* mg1  = (const float*)d_in[14];
    const float* mgb1 = (const float*)d_in[15];
    const float* mg2  = (const float*)d_in[16];
    const float* mgb2 = (const float*)d_in[17];

    char* ws = (char*)d_ws;
    bf16*  wqkT  = (bf16*)(ws);                // 768*256*2      = 393216
    bf16*  wv_b  = (bf16*)(ws + 393216);       // 147456*2       = 294912
    bf16*  fc_b  = (bf16*)(ws + 688128);       // 147456*2       = 294912
    bf16*  mg1_b = (bf16*)(ws + 983040);       // 65536*2        = 131072
    bf16*  mg2_b = (bf16*)(ws + 1114112);      // 16384*2        = 32768
    float* qwk   = (float*)(ws + 1146880);     // 8192*768*4     = 25165824
    bf16*  ctx   = (bf16*)(ws + 26312704);     // 8192*768*2     = 12582912  (ends 38895616)

    float* merged = (float*)d_out;
    float* attnw  = merged + (size_t)8192 * 128;

    k_wqk <<<48,   256, 0, stream>>>(wq, wk, wqkT);
    k_cvt <<<368,  256, 0, stream>>>(wv, fcw, mg1, mg2, wv_b, fc_b, mg1_b, mg2_b);
    k_qwk <<<256,  256, 0, stream>>>(src, srct, wqkT, qwk);
    k_attn<<<8192, 256, 0, stream>>>(seq, seqe, seqt, qwk, mask, attnw, ctx);
    k_tail<<<512,  256, 0, stream>>>(ctx, src, wv_b, fc_b, fcb, lng, lnb,
                                     mg1_b, mgb1, mg2_b, mgb2, merged);
}